// Round 5
// baseline (7868.253 us; speedup 1.0000x reference)
//
#include <hip/hip_runtime.h>

// LSTM_RNN: B=8192, T=2048, H=51, 2-layer LSTM + linear head.
// R9: dual-tile waves for guaranteed MFMA/VALU overlap. R8's split-phase
// regressed (imbalanced windows -> 19% barrier idle; reverted). R7 counters
// showed VALU(1900cyc) + MFMA(777cyc) per SIMD-step run strictly SERIAL
// (sum ~= step) because the 1-barrier schedule phase-aligns all waves. Fix
// with intra-wave ILP: MR=32 (two 16-row tiles per block, grid=256=1/CU);
// each wave owns two independent recurrence chains and its own stream
// interleaves act(tile-a) with MFMA(tile-b) via register deps. Per-row
// MFMA/VALU/LDS totals identical to R7; barriers per row halved; occupancy
// 16->8 waves/CU (R7 had zero cross-wave overlap, so nothing real is lost).
// Everything else as R7: packed-f32 activation (v_pk_*), fused i*g pair-rcp,
// batch-4 Montgomery f-rcp, pre-scaled cell state (-2L*c), fused
// sigma(o)*tanh(c), fp16 MFMA with x/bias K-slots 51/52, ROWW=72 rows,
// producer-consumer wave split, s_setprio, 1 barrier/step.

#define B_TOT 8192
#define T_LEN 2048
#define MR    32            // rows per block: two 16-row MFMA tiles
#define ROWW  72            // f16 per row: [h 0..50][x 51][1.0 52][0 ..63][pad]
#define HB    (MR*ROWW)     // 2304 f16 per parity buffer
#define T1    (16*ROWW)     // tile-b row offset within a buffer

typedef _Float16 f16x8 __attribute__((ext_vector_type(8)));
typedef float    f32x4 __attribute__((ext_vector_type(4)));
typedef float    f32x2 __attribute__((ext_vector_type(2)));

#define LOG2E 1.4426950408889634f

static __device__ __forceinline__ float us2f(unsigned short u) {
    unsigned int w = ((unsigned int)u) << 16;
    float f; __builtin_memcpy(&f, &w, 4);
    return f;
}
// load f32 from f32 or bf16 global
static __device__ __forceinline__ float ldf(const void* p, int idx, bool isbf) {
    return isbf ? us2f(((const unsigned short*)p)[idx])
                : ((const float*)p)[idx];
}
static __device__ __forceinline__ void store_y(void* outp, bool isbf, int idx, float v) {
    if (isbf) {
        unsigned int u; __builtin_memcpy(&u, &v, 4);
        u = (u + 0x7FFFu + ((u >> 16) & 1u)) >> 16;
        ((unsigned short*)outp)[idx] = (unsigned short)u;
    } else {
        ((float*)outp)[idx] = v;
    }
}

// Packed LSTM activation + cell/h update (identical math to R7).
// acc[n][r]: n=0 i (-L*z), n=1 f (-L*z), n=2 g (-2L*z), n=3 o (-L*z).
// C[p] = cell state rows {2p,2p+1}, pre-scaled by -2L. h[p] out.
template<bool CLAMP_G>
static __device__ __forceinline__ void lstm_act(const f32x4* acc, f32x2* C, f32x2* h) {
    f32x2 di[2], df[2], dg[2], dox[2];
    #pragma unroll
    for (int p = 0; p < 2; ++p) {
        f32x2 ei, ef, eg, eo;
        #pragma unroll
        for (int e = 0; e < 2; ++e) {
            const int r = 2*p + e;
            ei[e] = __builtin_amdgcn_exp2f(acc[0][r]);
            ef[e] = __builtin_amdgcn_exp2f(acc[1][r]);
            float ag = acc[2][r];
            if (CLAMP_G) ag = __builtin_amdgcn_fmed3f(ag, -30.0f, 30.0f);
            eg[e] = __builtin_amdgcn_exp2f(ag);
            eo[e] = __builtin_amdgcn_exp2f(acc[3][r]);
        }
        di[p]  = ei + 1.0f;
        df[p]  = ef + 1.0f;
        dg[p]  = eg + 1.0f;
        dox[p] = eo + 1.0f;
    }
    f32x2 q[2], sig[2];
    q[0] = di[0]*dg[0];
    q[1] = di[1]*dg[1];
    const float Ri0 = __builtin_amdgcn_rcpf(q[0].x*q[0].y);
    const float Ri1 = __builtin_amdgcn_rcpf(q[1].x*q[1].y);
    sig[0] = (dg[0]*(2.0f*LOG2E) + (-4.0f*LOG2E)) * (q[0].yx * Ri0);
    sig[1] = (dg[1]*(2.0f*LOG2E) + (-4.0f*LOG2E)) * (q[1].yx * Ri1);
    const float pf01 = df[0].x*df[0].y;
    const float pf23 = df[1].x*df[1].y;
    const float Rf   = __builtin_amdgcn_rcpf(pf01*pf23);
    const f32x2 sf0 = df[0].yx * (Rf*pf23);
    const f32x2 sf1 = df[1].yx * (Rf*pf01);
    f32x2 tt[2], m[2];
    {
        const f32x2 Cn = sf0*C[0] + sig[0];
        C[0] = Cn;
        f32x2 e2;
        e2.x = __builtin_amdgcn_exp2f(__builtin_amdgcn_fmed3f(Cn.x, -30.0f, 30.0f));
        e2.y = __builtin_amdgcn_exp2f(__builtin_amdgcn_fmed3f(Cn.y, -30.0f, 30.0f));
        tt[0] = e2 + 1.0f;
        m[0]  = dox[0]*tt[0];
    }
    {
        const f32x2 Cn = sf1*C[1] + sig[1];
        C[1] = Cn;
        f32x2 e2;
        e2.x = __builtin_amdgcn_exp2f(__builtin_amdgcn_fmed3f(Cn.x, -30.0f, 30.0f));
        e2.y = __builtin_amdgcn_exp2f(__builtin_amdgcn_fmed3f(Cn.y, -30.0f, 30.0f));
        tt[1] = e2 + 1.0f;
        m[1]  = dox[1]*tt[1];
    }
    const float Rc = __builtin_amdgcn_rcpf(m[0].x*m[0].y);
    const float Rd = __builtin_amdgcn_rcpf(m[1].x*m[1].y);
    h[0] = (2.0f - tt[0]) * (m[0].yx * Rc);
    h[1] = (2.0f - tt[1]) * (m[1].yx * Rd);
}

__global__ __launch_bounds__(512, 4)
void lstm2_kernel(const void* __restrict__ xin,
                  const void* __restrict__ Wih1, const void* __restrict__ Whh1,
                  const void* __restrict__ bih1, const void* __restrict__ bhh1,
                  const void* __restrict__ Wih2, const void* __restrict__ Whh2,
                  const void* __restrict__ bih2, const void* __restrict__ bhh2,
                  const void* __restrict__ Wlin, const void* __restrict__ blin,
                  void* __restrict__ outp)
{
    const int tid  = threadIdx.x;
    const int wset = tid >> 8;         // 0: layer-1 waves, 1: layer-2 waves
    const int wv   = (tid >> 6) & 3;   // j-slice within set
    const int ln   = tid & 63;
    const int lid  = ln & 15;
    const int quad = ln >> 4;
    const int b0   = blockIdx.x * MR;
    const int jcol = 13*wv + lid;
    const bool valid = (lid < 13) && (jcol < 51);
    const bool ylane = (wv == 3) && (lid == 12);   // pad col 51 -> y head

    __shared__ alignas(16) _Float16 hx [2*HB];   // h1 ping-pong + x/1.0 K-slots
    __shared__ alignas(16) _Float16 h2b[2*HB];   // h2 ping-pong

    // ---- dtype sniff (f32 vs bf16 globals), block-uniform ----
    bool isbf;
    {
        const unsigned short* xu = (const unsigned short*)xin;
        int cnt = 0;
        #pragma unroll
        for (int i = 0; i < 64; i += 2) {
            unsigned e = (xu[i] >> 7) & 0xFFu;
            cnt += (e >= 115u && e <= 131u) ? 1 : 0;
        }
        isbf = (cnt >= 16);
    }

    // ---- init LDS ----
    for (int i = tid; i < 2*HB; i += 512) {
        hx[i]  = (_Float16)0.0f;
        h2b[i] = (_Float16)0.0f;
    }
    __syncthreads();
    if (tid < MR) {
        hx[0*HB + tid*ROWW + 52] = (_Float16)1.0f;   // bias slot, both parities
        hx[1*HB + tid*ROWW + 52] = (_Float16)1.0f;
        hx[1*HB + tid*ROWW + 51] = (_Float16)ldf(xin, (b0 + tid)*T_LEN, isbf);
    }
    __syncthreads();

    if (wset == 0) {
        // ================= LAYER-1 WAVES =================
        f16x8 B1[4][2];
        #pragma unroll
        for (int n = 0; n < 4; ++n) {
            const int g = 51*n + jcol;
            const float sn = (n == 2) ? -2.0f*LOG2E : -LOG2E;
            #pragma unroll
            for (int kb = 0; kb < 2; ++kb) {
                f16x8 f;
                #pragma unroll
                for (int j8 = 0; j8 < 8; ++j8) {
                    const int k = kb*32 + quad*8 + j8;
                    float v = 0.0f;
                    if (valid) {
                        if (k < 51)       v = sn * ldf(Whh1, g*51 + k, isbf);
                        else if (k == 51) v = sn * ldf(Wih1, g, isbf);
                        else if (k == 52) v = sn * (ldf(bih1, g, isbf) + ldf(bhh1, g, isbf));
                    }
                    f[j8] = (_Float16)v;
                }
                B1[n][kb] = f;
            }
        }
        f32x2 c1a[2] = {{0.0f, 0.0f}, {0.0f, 0.0f}};
        f32x2 c1b[2] = {{0.0f, 0.0f}, {0.0f, 0.0f}};

        #pragma unroll 2
        for (int k = 0; k <= T_LEN; ++k) {
            if (k < T_LEN) {
                const int rs = (k - 1) & 1, ws = k & 1;
                // early x(k+1) prefetch (rows 0..31 -> first wave's 32 lanes)
                const bool xl = (tid < MR) && (k + 1 < T_LEN);
                float xnext = 0.0f;
                if (xl) xnext = ldf(xin, (b0 + tid)*T_LEN + k + 1, isbf);

                const _Float16* hpa = &hx[rs*HB + lid*ROWW + quad*8];
                const f16x8 a0 = *(const f16x8*)(hpa);
                const f16x8 a1 = *(const f16x8*)(hpa + 32);
                const f16x8 b0f = *(const f16x8*)(hpa + T1);
                const f16x8 b1f = *(const f16x8*)(hpa + T1 + 32);
                f32x4 accA[4], accB[4];
                __builtin_amdgcn_s_setprio(1);
                #pragma unroll
                for (int n = 0; n < 4; ++n) {
                    f32x4 z = {0.0f, 0.0f, 0.0f, 0.0f};
                    z       = __builtin_amdgcn_mfma_f32_16x16x32_f16(a0, B1[n][0], z, 0,0,0);
                    accA[n] = __builtin_amdgcn_mfma_f32_16x16x32_f16(a1, B1[n][1], z, 0,0,0);
                }
                #pragma unroll
                for (int n = 0; n < 4; ++n) {
                    f32x4 z = {0.0f, 0.0f, 0.0f, 0.0f};
                    z       = __builtin_amdgcn_mfma_f32_16x16x32_f16(b0f, B1[n][0], z, 0,0,0);
                    accB[n] = __builtin_amdgcn_mfma_f32_16x16x32_f16(b1f, B1[n][1], z, 0,0,0);
                }
                __builtin_amdgcn_s_setprio(0);
                // act tile-a overlaps tile-b's MFMAs in the pipe
                f32x2 ha[2], hb[2];
                lstm_act<false>(accA, c1a, ha);
                if (valid) {
                    _Float16* hw = &hx[ws*HB + (quad*4)*ROWW + jcol];
                    hw[0*ROWW] = (_Float16)ha[0].x;
                    hw[1*ROWW] = (_Float16)ha[0].y;
                    hw[2*ROWW] = (_Float16)ha[1].x;
                    hw[3*ROWW] = (_Float16)ha[1].y;
                }
                lstm_act<false>(accB, c1b, hb);
                if (valid) {
                    _Float16* hw = &hx[ws*HB + T1 + (quad*4)*ROWW + jcol];
                    hw[0*ROWW] = (_Float16)hb[0].x;
                    hw[1*ROWW] = (_Float16)hb[0].y;
                    hw[2*ROWW] = (_Float16)hb[1].x;
                    hw[3*ROWW] = (_Float16)hb[1].y;
                }
                if (xl) hx[ws*HB + tid*ROWW + 51] = (_Float16)xnext;
            }
            __syncthreads();
        }
    } else {
        // ================= LAYER-2 WAVES =================
        f16x8 B2i[4][2], B2h[4][2];
        #pragma unroll
        for (int n = 0; n < 4; ++n) {
            const int g = 51*n + jcol;
            const float sn = (n == 2) ? -2.0f*LOG2E : -LOG2E;
            #pragma unroll
            for (int kb = 0; kb < 2; ++kb) {
                f16x8 fi, fh;
                #pragma unroll
                for (int j8 = 0; j8 < 8; ++j8) {
                    const int k = kb*32 + quad*8 + j8;
                    float vi = 0.0f, vh = 0.0f;
                    if (valid) {
                        if (k < 51) {
                            vi = sn * ldf(Wih2, g*51 + k, isbf);
                            vh = sn * ldf(Whh2, g*51 + k, isbf);
                        } else if (k == 52) {
                            vi = sn * (ldf(bih2, g, isbf) + ldf(bhh2, g, isbf));
                        }
                    } else if (ylane && n == 3) {
                        if (k < 51)       vh = ldf(Wlin, k, isbf);
                        else if (k == 52) vi = ldf(blin, 0, isbf);
                    }
                    fi[j8] = (_Float16)vi; fh[j8] = (_Float16)vh;
                }
                B2i[n][kb] = fi; B2h[n][kb] = fh;
            }
        }
        const float bl = ldf(blin, 0, isbf);
        f32x2 c2a[2] = {{0.0f, 0.0f}, {0.0f, 0.0f}};
        f32x2 c2b[2] = {{0.0f, 0.0f}, {0.0f, 0.0f}};

        #pragma unroll 2
        for (int k = 0; k <= T_LEN; ++k) {
            if (k >= 1) {
                const int rs1 = (k - 1) & 1;   // h1(k-1) + x/bias slots
                const int rs2 = k & 1;         // h2(k-2)
                const int ws2 = (k - 1) & 1;   // h2(k-1)
                const _Float16* h1p = &hx [rs1*HB + lid*ROWW + quad*8];
                const _Float16* h2p = &h2b[rs2*HB + lid*ROWW + quad*8];
                const f16x8 p0 = *(const f16x8*)(h1p);
                const f16x8 p1 = *(const f16x8*)(h1p + 32);
                const f16x8 q0 = *(const f16x8*)(h2p);
                const f16x8 q1 = *(const f16x8*)(h2p + 32);
                const f16x8 p0b = *(const f16x8*)(h1p + T1);
                const f16x8 p1b = *(const f16x8*)(h1p + T1 + 32);
                const f16x8 q0b = *(const f16x8*)(h2p + T1);
                const f16x8 q1b = *(const f16x8*)(h2p + T1 + 32);
                f32x4 accA[4], accB[4];
                __builtin_amdgcn_s_setprio(1);
                #pragma unroll
                for (int n = 0; n < 4; ++n) {
                    f32x4 z = {0.0f, 0.0f, 0.0f, 0.0f};
                    z       = __builtin_amdgcn_mfma_f32_16x16x32_f16(p0, B2i[n][0], z, 0,0,0);
                    z       = __builtin_amdgcn_mfma_f32_16x16x32_f16(p1, B2i[n][1], z, 0,0,0);
                    z       = __builtin_amdgcn_mfma_f32_16x16x32_f16(q0, B2h[n][0], z, 0,0,0);
                    accA[n] = __builtin_amdgcn_mfma_f32_16x16x32_f16(q1, B2h[n][1], z, 0,0,0);
                }
                #pragma unroll
                for (int n = 0; n < 4; ++n) {
                    f32x4 z = {0.0f, 0.0f, 0.0f, 0.0f};
                    z       = __builtin_amdgcn_mfma_f32_16x16x32_f16(p0b, B2i[n][0], z, 0,0,0);
                    z       = __builtin_amdgcn_mfma_f32_16x16x32_f16(p1b, B2i[n][1], z, 0,0,0);
                    z       = __builtin_amdgcn_mfma_f32_16x16x32_f16(q0b, B2h[n][0], z, 0,0,0);
                    accB[n] = __builtin_amdgcn_mfma_f32_16x16x32_f16(q1b, B2h[n][1], z, 0,0,0);
                }
                __builtin_amdgcn_s_setprio(0);
                if (ylane && k >= 2) {   // pad col: blin + Wlin.h2(k-2) = y[k-2]
                    #pragma unroll
                    for (int r = 0; r < 4; ++r) {
                        store_y(outp, isbf, (b0 + quad*4 + r)*T_LEN + (k - 2), accA[3][r]);
                        store_y(outp, isbf, (b0 + 16 + quad*4 + r)*T_LEN + (k - 2), accB[3][r]);
                    }
                }
                f32x2 ha[2], hb[2];
                lstm_act<true>(accA, c2a, ha);   // overlaps tile-b MFMAs
                if (valid) {
                    _Float16* hw = &h2b[ws2*HB + (quad*4)*ROWW + jcol];
                    hw[0*ROWW] = (_Float16)ha[0].x;
                    hw[1*ROWW] = (_Float16)ha[0].y;
                    hw[2*ROWW] = (_Float16)ha[1].x;
                    hw[3*ROWW] = (_Float16)ha[1].y;
                }
                lstm_act<true>(accB, c2b, hb);
                if (valid) {
                    _Float16* hw = &h2b[ws2*HB + T1 + (quad*4)*ROWW + jcol];
                    hw[0*ROWW] = (_Float16)hb[0].x;
                    hw[1*ROWW] = (_Float16)hb[0].y;
                    hw[2*ROWW] = (_Float16)hb[1].x;
                    hw[3*ROWW] = (_Float16)hb[1].y;
                }
            }
            __syncthreads();
        }

        // ---- flush y[T-1] from final h2 (parity (T-1)&1) ----
        if (wv == 3) {
            const _Float16* h2p = &h2b[((T_LEN - 1) & 1)*HB + lid*ROWW + quad*8];
            const f16x8 q0 = *(const f16x8*)(h2p);
            const f16x8 q1 = *(const f16x8*)(h2p + 32);
            const f16x8 q0b = *(const f16x8*)(h2p + T1);
            const f16x8 q1b = *(const f16x8*)(h2p + T1 + 32);
            f32x4 za = {bl, bl, bl, bl};
            za = __builtin_amdgcn_mfma_f32_16x16x32_f16(q0, B2h[3][0], za, 0,0,0);
            za = __builtin_amdgcn_mfma_f32_16x16x32_f16(q1, B2h[3][1], za, 0,0,0);
            f32x4 zb = {bl, bl, bl, bl};
            zb = __builtin_amdgcn_mfma_f32_16x16x32_f16(q0b, B2h[3][0], zb, 0,0,0);
            zb = __builtin_amdgcn_mfma_f32_16x16x32_f16(q1b, B2h[3][1], zb, 0,0,0);
            if (lid == 12) {
                #pragma unroll
                for (int r = 0; r < 4; ++r) {
                    store_y(outp, isbf, (b0 + quad*4 + r)*T_LEN + (T_LEN - 1), za[r]);
                    store_y(outp, isbf, (b0 + 16 + quad*4 + r)*T_LEN + (T_LEN - 1), zb[r]);
                }
            }
        }
    }
}

extern "C" void kernel_launch(void* const* d_in, const int* in_sizes, int n_in,
                              void* d_out, int out_size, void* d_ws, size_t ws_size,
                              hipStream_t stream) {
    (void)in_sizes; (void)n_in; (void)out_size; (void)d_ws; (void)ws_size;
    dim3 grid(B_TOT / MR), block(512);
    lstm2_kernel<<<grid, block, 0, stream>>>(
        d_in[0], d_in[1], d_in[2], d_in[3], d_in[4], d_in[5],
        d_in[6], d_in[7], d_in[8], d_in[9], d_in[10], d_out);
}

// Round 6
// 2735.778 us; speedup vs baseline: 2.8761x; 2.8761x over previous
//
#include <hip/hip_runtime.h>

// LSTM_RNN: B=8192, T=2048, H=51, 2-layer LSTM + linear head.
// R10 = R9 schedule with the spill fixed. R9's dual-tile state (~180 VGPR)
// was register-capped by __launch_bounds__(512,4) -> accB/c-state spilled to
// scratch (FETCH 36.5->461MB, WRITE 71MB->1.06GB, 3.4x dur). With MR=32 the
// grid is 256 = 1 block/CU = 2 waves/SIMD REGARDLESS of the bound, so
// __launch_bounds__(512,2) lifts the VGPR cap to 256 at zero occupancy cost.
// Mechanism under test (from R7 counters: VALU 1900cyc + MFMA 777cyc per
// SIMD-step, strictly serial): each wave owns two independent 16-row
// recurrence chains; its stream issues MFMA(a), MFMA(b), then act(a) on the
// VALU while MFMA(b) drains the matrix pipe - overlap enforced by register
// deps, no scheduler luck, no extra barriers. Per-CU MFMA/VALU/LDS totals
// identical to R7; barriers per row halved. Everything else as R7: packed
// f32 activation (v_pk_*), fused i*g pair-rcp, batch-4 Montgomery f-rcp,
// pre-scaled cell state (-2L*c), fused sigma(o)*tanh(c), fp16 MFMA with
// x/bias K-slots 51/52, ROWW=72, producer-consumer wave split, s_setprio.

#define B_TOT 8192
#define T_LEN 2048
#define MR    32            // rows per block: two 16-row MFMA tiles
#define ROWW  72            // f16 per row: [h 0..50][x 51][1.0 52][0 ..63][pad]
#define HB    (MR*ROWW)     // 2304 f16 per parity buffer
#define T1    (16*ROWW)     // tile-b row offset within a buffer

typedef _Float16 f16x8 __attribute__((ext_vector_type(8)));
typedef float    f32x4 __attribute__((ext_vector_type(4)));
typedef float    f32x2 __attribute__((ext_vector_type(2)));

#define LOG2E 1.4426950408889634f

static __device__ __forceinline__ float us2f(unsigned short u) {
    unsigned int w = ((unsigned int)u) << 16;
    float f; __builtin_memcpy(&f, &w, 4);
    return f;
}
// load f32 from f32 or bf16 global
static __device__ __forceinline__ float ldf(const void* p, int idx, bool isbf) {
    return isbf ? us2f(((const unsigned short*)p)[idx])
                : ((const float*)p)[idx];
}
static __device__ __forceinline__ void store_y(void* outp, bool isbf, int idx, float v) {
    if (isbf) {
        unsigned int u; __builtin_memcpy(&u, &v, 4);
        u = (u + 0x7FFFu + ((u >> 16) & 1u)) >> 16;
        ((unsigned short*)outp)[idx] = (unsigned short)u;
    } else {
        ((float*)outp)[idx] = v;
    }
}

// Packed LSTM activation + cell/h update (identical math to R7).
// acc[n][r]: n=0 i (-L*z), n=1 f (-L*z), n=2 g (-2L*z), n=3 o (-L*z).
// C[p] = cell state rows {2p,2p+1}, pre-scaled by -2L. h[p] out.
template<bool CLAMP_G>
static __device__ __forceinline__ void lstm_act(const f32x4* acc, f32x2* C, f32x2* h) {
    f32x2 di[2], df[2], dg[2], dox[2];
    #pragma unroll
    for (int p = 0; p < 2; ++p) {
        f32x2 ei, ef, eg, eo;
        #pragma unroll
        for (int e = 0; e < 2; ++e) {
            const int r = 2*p + e;
            ei[e] = __builtin_amdgcn_exp2f(acc[0][r]);
            ef[e] = __builtin_amdgcn_exp2f(acc[1][r]);
            float ag = acc[2][r];
            if (CLAMP_G) ag = __builtin_amdgcn_fmed3f(ag, -30.0f, 30.0f);
            eg[e] = __builtin_amdgcn_exp2f(ag);
            eo[e] = __builtin_amdgcn_exp2f(acc[3][r]);
        }
        di[p]  = ei + 1.0f;
        df[p]  = ef + 1.0f;
        dg[p]  = eg + 1.0f;
        dox[p] = eo + 1.0f;
    }
    f32x2 q[2], sig[2];
    q[0] = di[0]*dg[0];
    q[1] = di[1]*dg[1];
    const float Ri0 = __builtin_amdgcn_rcpf(q[0].x*q[0].y);
    const float Ri1 = __builtin_amdgcn_rcpf(q[1].x*q[1].y);
    sig[0] = (dg[0]*(2.0f*LOG2E) + (-4.0f*LOG2E)) * (q[0].yx * Ri0);
    sig[1] = (dg[1]*(2.0f*LOG2E) + (-4.0f*LOG2E)) * (q[1].yx * Ri1);
    const float pf01 = df[0].x*df[0].y;
    const float pf23 = df[1].x*df[1].y;
    const float Rf   = __builtin_amdgcn_rcpf(pf01*pf23);
    const f32x2 sf0 = df[0].yx * (Rf*pf23);
    const f32x2 sf1 = df[1].yx * (Rf*pf01);
    f32x2 tt[2], m[2];
    {
        const f32x2 Cn = sf0*C[0] + sig[0];
        C[0] = Cn;
        f32x2 e2;
        e2.x = __builtin_amdgcn_exp2f(__builtin_amdgcn_fmed3f(Cn.x, -30.0f, 30.0f));
        e2.y = __builtin_amdgcn_exp2f(__builtin_amdgcn_fmed3f(Cn.y, -30.0f, 30.0f));
        tt[0] = e2 + 1.0f;
        m[0]  = dox[0]*tt[0];
    }
    {
        const f32x2 Cn = sf1*C[1] + sig[1];
        C[1] = Cn;
        f32x2 e2;
        e2.x = __builtin_amdgcn_exp2f(__builtin_amdgcn_fmed3f(Cn.x, -30.0f, 30.0f));
        e2.y = __builtin_amdgcn_exp2f(__builtin_amdgcn_fmed3f(Cn.y, -30.0f, 30.0f));
        tt[1] = e2 + 1.0f;
        m[1]  = dox[1]*tt[1];
    }
    const float Rc = __builtin_amdgcn_rcpf(m[0].x*m[0].y);
    const float Rd = __builtin_amdgcn_rcpf(m[1].x*m[1].y);
    h[0] = (2.0f - tt[0]) * (m[0].yx * Rc);
    h[1] = (2.0f - tt[1]) * (m[1].yx * Rd);
}

__global__ __launch_bounds__(512, 2)
void lstm2_kernel(const void* __restrict__ xin,
                  const void* __restrict__ Wih1, const void* __restrict__ Whh1,
                  const void* __restrict__ bih1, const void* __restrict__ bhh1,
                  const void* __restrict__ Wih2, const void* __restrict__ Whh2,
                  const void* __restrict__ bih2, const void* __restrict__ bhh2,
                  const void* __restrict__ Wlin, const void* __restrict__ blin,
                  void* __restrict__ outp)
{
    const int tid  = threadIdx.x;
    const int wset = tid >> 8;         // 0: layer-1 waves, 1: layer-2 waves
    const int wv   = (tid >> 6) & 3;   // j-slice within set
    const int ln   = tid & 63;
    const int lid  = ln & 15;
    const int quad = ln >> 4;
    const int b0   = blockIdx.x * MR;
    const int jcol = 13*wv + lid;
    const bool valid = (lid < 13) && (jcol < 51);
    const bool ylane = (wv == 3) && (lid == 12);   // pad col 51 -> y head

    __shared__ alignas(16) _Float16 hx [2*HB];   // h1 ping-pong + x/1.0 K-slots
    __shared__ alignas(16) _Float16 h2b[2*HB];   // h2 ping-pong

    // ---- dtype sniff (f32 vs bf16 globals), block-uniform ----
    bool isbf;
    {
        const unsigned short* xu = (const unsigned short*)xin;
        int cnt = 0;
        #pragma unroll
        for (int i = 0; i < 64; i += 2) {
            unsigned e = (xu[i] >> 7) & 0xFFu;
            cnt += (e >= 115u && e <= 131u) ? 1 : 0;
        }
        isbf = (cnt >= 16);
    }

    // ---- init LDS ----
    for (int i = tid; i < 2*HB; i += 512) {
        hx[i]  = (_Float16)0.0f;
        h2b[i] = (_Float16)0.0f;
    }
    __syncthreads();
    if (tid < MR) {
        hx[0*HB + tid*ROWW + 52] = (_Float16)1.0f;   // bias slot, both parities
        hx[1*HB + tid*ROWW + 52] = (_Float16)1.0f;
        hx[1*HB + tid*ROWW + 51] = (_Float16)ldf(xin, (b0 + tid)*T_LEN, isbf);
    }
    __syncthreads();

    if (wset == 0) {
        // ================= LAYER-1 WAVES =================
        f16x8 B1[4][2];
        #pragma unroll
        for (int n = 0; n < 4; ++n) {
            const int g = 51*n + jcol;
            const float sn = (n == 2) ? -2.0f*LOG2E : -LOG2E;
            #pragma unroll
            for (int kb = 0; kb < 2; ++kb) {
                f16x8 f;
                #pragma unroll
                for (int j8 = 0; j8 < 8; ++j8) {
                    const int k = kb*32 + quad*8 + j8;
                    float v = 0.0f;
                    if (valid) {
                        if (k < 51)       v = sn * ldf(Whh1, g*51 + k, isbf);
                        else if (k == 51) v = sn * ldf(Wih1, g, isbf);
                        else if (k == 52) v = sn * (ldf(bih1, g, isbf) + ldf(bhh1, g, isbf));
                    }
                    f[j8] = (_Float16)v;
                }
                B1[n][kb] = f;
            }
        }
        f32x2 c1a[2] = {{0.0f, 0.0f}, {0.0f, 0.0f}};
        f32x2 c1b[2] = {{0.0f, 0.0f}, {0.0f, 0.0f}};

        #pragma unroll 2
        for (int k = 0; k <= T_LEN; ++k) {
            if (k < T_LEN) {
                const int rs = (k - 1) & 1, ws = k & 1;
                // early x(k+1) prefetch (rows 0..31 -> first wave's 32 lanes)
                const bool xl = (tid < MR) && (k + 1 < T_LEN);
                float xnext = 0.0f;
                if (xl) xnext = ldf(xin, (b0 + tid)*T_LEN + k + 1, isbf);

                const _Float16* hpa = &hx[rs*HB + lid*ROWW + quad*8];
                const f16x8 a0 = *(const f16x8*)(hpa);
                const f16x8 a1 = *(const f16x8*)(hpa + 32);
                const f16x8 b0f = *(const f16x8*)(hpa + T1);
                const f16x8 b1f = *(const f16x8*)(hpa + T1 + 32);
                f32x4 accA[4], accB[4];
                __builtin_amdgcn_s_setprio(1);
                #pragma unroll
                for (int n = 0; n < 4; ++n) {
                    f32x4 z = {0.0f, 0.0f, 0.0f, 0.0f};
                    z       = __builtin_amdgcn_mfma_f32_16x16x32_f16(a0, B1[n][0], z, 0,0,0);
                    accA[n] = __builtin_amdgcn_mfma_f32_16x16x32_f16(a1, B1[n][1], z, 0,0,0);
                }
                #pragma unroll
                for (int n = 0; n < 4; ++n) {
                    f32x4 z = {0.0f, 0.0f, 0.0f, 0.0f};
                    z       = __builtin_amdgcn_mfma_f32_16x16x32_f16(b0f, B1[n][0], z, 0,0,0);
                    accB[n] = __builtin_amdgcn_mfma_f32_16x16x32_f16(b1f, B1[n][1], z, 0,0,0);
                }
                __builtin_amdgcn_s_setprio(0);
                // act tile-a overlaps tile-b's MFMAs in the pipe
                f32x2 ha[2], hb[2];
                lstm_act<false>(accA, c1a, ha);
                if (valid) {
                    _Float16* hw = &hx[ws*HB + (quad*4)*ROWW + jcol];
                    hw[0*ROWW] = (_Float16)ha[0].x;
                    hw[1*ROWW] = (_Float16)ha[0].y;
                    hw[2*ROWW] = (_Float16)ha[1].x;
                    hw[3*ROWW] = (_Float16)ha[1].y;
                }
                lstm_act<false>(accB, c1b, hb);
                if (valid) {
                    _Float16* hw = &hx[ws*HB + T1 + (quad*4)*ROWW + jcol];
                    hw[0*ROWW] = (_Float16)hb[0].x;
                    hw[1*ROWW] = (_Float16)hb[0].y;
                    hw[2*ROWW] = (_Float16)hb[1].x;
                    hw[3*ROWW] = (_Float16)hb[1].y;
                }
                if (xl) hx[ws*HB + tid*ROWW + 51] = (_Float16)xnext;
            }
            __syncthreads();
        }
    } else {
        // ================= LAYER-2 WAVES =================
        f16x8 B2i[4][2], B2h[4][2];
        #pragma unroll
        for (int n = 0; n < 4; ++n) {
            const int g = 51*n + jcol;
            const float sn = (n == 2) ? -2.0f*LOG2E : -LOG2E;
            #pragma unroll
            for (int kb = 0; kb < 2; ++kb) {
                f16x8 fi, fh;
                #pragma unroll
                for (int j8 = 0; j8 < 8; ++j8) {
                    const int k = kb*32 + quad*8 + j8;
                    float vi = 0.0f, vh = 0.0f;
                    if (valid) {
                        if (k < 51) {
                            vi = sn * ldf(Wih2, g*51 + k, isbf);
                            vh = sn * ldf(Whh2, g*51 + k, isbf);
                        } else if (k == 52) {
                            vi = sn * (ldf(bih2, g, isbf) + ldf(bhh2, g, isbf));
                        }
                    } else if (ylane && n == 3) {
                        if (k < 51)       vh = ldf(Wlin, k, isbf);
                        else if (k == 52) vi = ldf(blin, 0, isbf);
                    }
                    fi[j8] = (_Float16)vi; fh[j8] = (_Float16)vh;
                }
                B2i[n][kb] = fi; B2h[n][kb] = fh;
            }
        }
        const float bl = ldf(blin, 0, isbf);
        f32x2 c2a[2] = {{0.0f, 0.0f}, {0.0f, 0.0f}};
        f32x2 c2b[2] = {{0.0f, 0.0f}, {0.0f, 0.0f}};

        #pragma unroll 2
        for (int k = 0; k <= T_LEN; ++k) {
            if (k >= 1) {
                const int rs1 = (k - 1) & 1;   // h1(k-1) + x/bias slots
                const int rs2 = k & 1;         // h2(k-2)
                const int ws2 = (k - 1) & 1;   // h2(k-1)
                const _Float16* h1p = &hx [rs1*HB + lid*ROWW + quad*8];
                const _Float16* h2p = &h2b[rs2*HB + lid*ROWW + quad*8];
                const f16x8 p0 = *(const f16x8*)(h1p);
                const f16x8 p1 = *(const f16x8*)(h1p + 32);
                const f16x8 q0 = *(const f16x8*)(h2p);
                const f16x8 q1 = *(const f16x8*)(h2p + 32);
                const f16x8 p0b = *(const f16x8*)(h1p + T1);
                const f16x8 p1b = *(const f16x8*)(h1p + T1 + 32);
                const f16x8 q0b = *(const f16x8*)(h2p + T1);
                const f16x8 q1b = *(const f16x8*)(h2p + T1 + 32);
                f32x4 accA[4], accB[4];
                __builtin_amdgcn_s_setprio(1);
                #pragma unroll
                for (int n = 0; n < 4; ++n) {
                    f32x4 z = {0.0f, 0.0f, 0.0f, 0.0f};
                    z       = __builtin_amdgcn_mfma_f32_16x16x32_f16(p0, B2i[n][0], z, 0,0,0);
                    z       = __builtin_amdgcn_mfma_f32_16x16x32_f16(p1, B2i[n][1], z, 0,0,0);
                    z       = __builtin_amdgcn_mfma_f32_16x16x32_f16(q0, B2h[n][0], z, 0,0,0);
                    accA[n] = __builtin_amdgcn_mfma_f32_16x16x32_f16(q1, B2h[n][1], z, 0,0,0);
                }
                #pragma unroll
                for (int n = 0; n < 4; ++n) {
                    f32x4 z = {0.0f, 0.0f, 0.0f, 0.0f};
                    z       = __builtin_amdgcn_mfma_f32_16x16x32_f16(p0b, B2i[n][0], z, 0,0,0);
                    z       = __builtin_amdgcn_mfma_f32_16x16x32_f16(p1b, B2i[n][1], z, 0,0,0);
                    z       = __builtin_amdgcn_mfma_f32_16x16x32_f16(q0b, B2h[n][0], z, 0,0,0);
                    accB[n] = __builtin_amdgcn_mfma_f32_16x16x32_f16(q1b, B2h[n][1], z, 0,0,0);
                }
                __builtin_amdgcn_s_setprio(0);
                if (ylane && k >= 2) {   // pad col: blin + Wlin.h2(k-2) = y[k-2]
                    #pragma unroll
                    for (int r = 0; r < 4; ++r) {
                        store_y(outp, isbf, (b0 + quad*4 + r)*T_LEN + (k - 2), accA[3][r]);
                        store_y(outp, isbf, (b0 + 16 + quad*4 + r)*T_LEN + (k - 2), accB[3][r]);
                    }
                }
                f32x2 ha[2], hb[2];
                lstm_act<true>(accA, c2a, ha);   // overlaps tile-b MFMAs
                if (valid) {
                    _Float16* hw = &h2b[ws2*HB + (quad*4)*ROWW + jcol];
                    hw[0*ROWW] = (_Float16)ha[0].x;
                    hw[1*ROWW] = (_Float16)ha[0].y;
                    hw[2*ROWW] = (_Float16)ha[1].x;
                    hw[3*ROWW] = (_Float16)ha[1].y;
                }
                lstm_act<true>(accB, c2b, hb);
                if (valid) {
                    _Float16* hw = &h2b[ws2*HB + T1 + (quad*4)*ROWW + jcol];
                    hw[0*ROWW] = (_Float16)hb[0].x;
                    hw[1*ROWW] = (_Float16)hb[0].y;
                    hw[2*ROWW] = (_Float16)hb[1].x;
                    hw[3*ROWW] = (_Float16)hb[1].y;
                }
            }
            __syncthreads();
        }

        // ---- flush y[T-1] from final h2 (parity (T-1)&1) ----
        if (wv == 3) {
            const _Float16* h2p = &h2b[((T_LEN - 1) & 1)*HB + lid*ROWW + quad*8];
            const f16x8 q0 = *(const f16x8*)(h2p);
            const f16x8 q1 = *(const f16x8*)(h2p + 32);
            const f16x8 q0b = *(const f16x8*)(h2p + T1);
            const f16x8 q1b = *(const f16x8*)(h2p + T1 + 32);
            f32x4 za = {bl, bl, bl, bl};
            za = __builtin_amdgcn_mfma_f32_16x16x32_f16(q0, B2h[3][0], za, 0,0,0);
            za = __builtin_amdgcn_mfma_f32_16x16x32_f16(q1, B2h[3][1], za, 0,0,0);
            f32x4 zb = {bl, bl, bl, bl};
            zb = __builtin_amdgcn_mfma_f32_16x16x32_f16(q0b, B2h[3][0], zb, 0,0,0);
            zb = __builtin_amdgcn_mfma_f32_16x16x32_f16(q1b, B2h[3][1], zb, 0,0,0);
            if (lid == 12) {
                #pragma unroll
                for (int r = 0; r < 4; ++r) {
                    store_y(outp, isbf, (b0 + quad*4 + r)*T_LEN + (T_LEN - 1), za[r]);
                    store_y(outp, isbf, (b0 + 16 + quad*4 + r)*T_LEN + (T_LEN - 1), zb[r]);
                }
            }
        }
    }
}

extern "C" void kernel_launch(void* const* d_in, const int* in_sizes, int n_in,
                              void* d_out, int out_size, void* d_ws, size_t ws_size,
                              hipStream_t stream) {
    (void)in_sizes; (void)n_in; (void)out_size; (void)d_ws; (void)ws_size;
    dim3 grid(B_TOT / MR), block(512);
    lstm2_kernel<<<grid, block, 0, stream>>>(
        d_in[0], d_in[1], d_in[2], d_in[3], d_in[4], d_in[5],
        d_in[6], d_in[7], d_in[8], d_in[9], d_in[10], d_out);
}